// Round 1
// baseline (269.207 us; speedup 1.0000x reference)
//
#include <hip/hip_runtime.h>

#define HH 12
#define DD 64
#define NB1 28
#define NB2 52
#define NF 2
#define SS 2912          // NF*NB1*NB2
#define FB1 56           // NF*NB1
#define FB2 104          // NF*NB2
#define STRIDE_HD 768    // HH*DD
#define SCALEF 0.125f

typedef float f32x4 __attribute__((ext_vector_type(4)));
typedef short bf16x8 __attribute__((ext_vector_type(8)));

__device__ __forceinline__ unsigned short f2bf(float x) {
  union { float f; unsigned u; } c; c.f = x;
  unsigned r = c.u + 0x7fffu + ((c.u >> 16) & 1u);
  return (unsigned short)(r >> 16);
}

// ---------------------------------------------------------------------------
// Fused blin(+rope) + tiny SDPA + output rope for one (group, head).
// lk path: NK=52, GD=28, GMUL=52, KSTR=1   (keys = b2, group = (f,b1))
// rq path: NK=28, GD=52, GMUL=1,  KSTR=52  (keys = b1, group = (f,j))
// q row input = xs[0] (s_base row); q and output rope use cos/sin at s_base.
// ---------------------------------------------------------------------------
template<int NK, int GD, int GMUL, int KSTR>
__global__ __launch_bounds__(256)
void k_small(const float* __restrict__ X,
             const float* __restrict__ cosb, const float* __restrict__ sinb,
             const float* __restrict__ Wq, const float* __restrict__ bq,
             const float* __restrict__ Wk, const float* __restrict__ bk,
             const float* __restrict__ Wv, const float* __restrict__ bv,
             float* __restrict__ outb) {
  const int n = blockIdx.x, h = blockIdx.y;
  const int tid = threadIdx.x;
  const int f = n / GD, g = n % GD;
  const int s_base = f * (NB1 * NB2) + g * GMUL;

  __shared__ __align__(16) float xs[NK][DD + 4];
  __shared__ float Ks[NK][DD + 1];
  __shared__ float Vs[NK][DD + 1];
  __shared__ float qs[DD];
  __shared__ float ps[64];

  // stage input rows (raw, pre-projection)
  for (int idx = tid; idx < NK * DD; idx += 256) {
    int r = idx >> 6, d = idx & 63;
    xs[r][d] = X[(size_t)(s_base + r * KSTR) * STRIDE_HD + h * DD + d];
  }
  __syncthreads();

  const int m  = tid >> 3;   // e-pair 0..31
  const int rg = tid & 7;    // row group 0..7
  const float* WkH = Wk + (size_t)h * DD * DD;
  const float* WvH = Wv + (size_t)h * DD * DD;
  const float bk0 = bk[h * DD + 2 * m], bk1 = bk[h * DD + 2 * m + 1];
  const float bv0 = bv[h * DD + 2 * m], bv1 = bv[h * DD + 2 * m + 1];
  const float4* wk0 = (const float4*)(WkH + (2 * m) * DD);
  const float4* wk1 = (const float4*)(WkH + (2 * m + 1) * DD);
  const float4* wv0 = (const float4*)(WvH + (2 * m) * DD);
  const float4* wv1 = (const float4*)(WvH + (2 * m + 1) * DD);

  // fused K (rope) + V projections, 2 rows per thread per base
  for (int base = 0; base < NK; base += 16) {
    for (int rr = 0; rr < 2; ++rr) {
      int r = base + 2 * rg + rr;
      if (r < NK) {
        float k0 = bk0, k1 = bk1, v0 = bv0, v1 = bv1;
        const float4* x4 = (const float4*)xs[r];
        #pragma unroll
        for (int d4 = 0; d4 < 16; ++d4) {
          float4 xv = x4[d4];
          float4 a = wk0[d4], b = wk1[d4], c = wv0[d4], e = wv1[d4];
          k0 += xv.x * a.x + xv.y * a.y + xv.z * a.z + xv.w * a.w;
          k1 += xv.x * b.x + xv.y * b.y + xv.z * b.z + xv.w * b.w;
          v0 += xv.x * c.x + xv.y * c.y + xv.z * c.z + xv.w * c.w;
          v1 += xv.x * e.x + xv.y * e.y + xv.z * e.z + xv.w * e.w;
        }
        int srow = s_base + r * KSTR;
        float co = cosb[srow * 32 + m], si = sinb[srow * 32 + m];
        Ks[r][2 * m]     = k0 * co - k1 * si;
        Ks[r][2 * m + 1] = k1 * co + k0 * si;
        Vs[r][2 * m]     = v0;
        Vs[r][2 * m + 1] = v1;
      }
    }
  }
  // q projection from xs[0], rope at s_base
  if (rg == 0) {
    float q0 = bq[h * DD + 2 * m], q1 = bq[h * DD + 2 * m + 1];
    const float4* x4 = (const float4*)xs[0];
    const float4* w0 = (const float4*)(Wq + (size_t)h * DD * DD + (2 * m) * DD);
    const float4* w1 = (const float4*)(Wq + (size_t)h * DD * DD + (2 * m + 1) * DD);
    #pragma unroll
    for (int d4 = 0; d4 < 16; ++d4) {
      float4 xv = x4[d4];
      float4 a = w0[d4], b = w1[d4];
      q0 += xv.x * a.x + xv.y * a.y + xv.z * a.z + xv.w * a.w;
      q1 += xv.x * b.x + xv.y * b.y + xv.z * b.z + xv.w * b.w;
    }
    float co = cosb[s_base * 32 + m], si = sinb[s_base * 32 + m];
    qs[2 * m]     = q0 * co - q1 * si;
    qs[2 * m + 1] = q1 * co + q0 * si;
  }
  __syncthreads();

  // scores + softmax on wave 0
  if (tid < 64) {
    float sc = -1e30f;
    if (tid < NK) {
      float acc2 = 0.f;
      const float* kr = Ks[tid];
      #pragma unroll 8
      for (int d = 0; d < DD; ++d) acc2 += qs[d] * kr[d];
      sc = acc2 * SCALEF;
    }
    float mx = sc;
    for (int o = 32; o; o >>= 1) mx = fmaxf(mx, __shfl_xor(mx, o));
    float e = (tid < NK) ? __expf(sc - mx) : 0.f;
    float sm = e;
    for (int o = 32; o; o >>= 1) sm += __shfl_xor(sm, o);
    if (tid < NK) ps[tid] = e / sm;
  }
  __syncthreads();

  // PV + output rope (32 threads)
  if (tid < 32) {
    float o0 = 0.f, o1 = 0.f;
    for (int r = 0; r < NK; ++r) {
      float p = ps[r];
      o0 += p * Vs[r][2 * tid];
      o1 += p * Vs[r][2 * tid + 1];
    }
    float co = cosb[s_base * 32 + tid], si = sinb[s_base * 32 + tid];
    outb[(size_t)n * STRIDE_HD + h * DD + 2 * tid]     = o0 * co - o1 * si;
    outb[(size_t)n * STRIDE_HD + h * DD + 2 * tid + 1] = o1 * co + o0 * si;
  }
}

// ---------------------------------------------------------------------------
// L[h,a,f,j,i,k] = sum_d rope(lq)[a,i,j,h,d] * lk_out[f,k,h,d]
// stored as Lbuf[(h*F+a)*B2 + j][f][i][k]
// ---------------------------------------------------------------------------
__global__ __launch_bounds__(256)
void k_L(const float* __restrict__ lq, const float* __restrict__ cosb,
         const float* __restrict__ sinb, const float* __restrict__ lk_out,
         float* __restrict__ Lbuf) {
  const int bid = blockIdx.x;              // h*104 + a*52 + j
  const int h = bid / (NF * NB2);
  const int rem = bid % (NF * NB2);
  const int a = rem / NB2, j = rem % NB2;
  const int tid = threadIdx.x;
  __shared__ __align__(16) float qs[NB1][DD + 8];
  __shared__ __align__(16) float ks[FB1][DD + 8];
  for (int idx = tid; idx < NB1 * 32; idx += 256) {
    int i = idx >> 5, mm = idx & 31;
    int srow = a * (NB1 * NB2) + i * NB2 + j;
    const float* xr = lq + (size_t)srow * STRIDE_HD + h * DD;
    float x0 = xr[2 * mm], x1 = xr[2 * mm + 1];
    float co = cosb[srow * 32 + mm], si = sinb[srow * 32 + mm];
    qs[i][2 * mm]     = x0 * co - x1 * si;
    qs[i][2 * mm + 1] = x1 * co + x0 * si;
  }
  for (int idx = tid; idx < FB1 * DD; idx += 256) {
    int r = idx >> 6, d = idx & 63;
    ks[r][d] = lk_out[(size_t)r * STRIDE_HD + h * DD + d];
  }
  __syncthreads();
  for (int idx = tid; idx < NF * NB1 * NB1; idx += 256) {   // 1568
    int ff = idx / (NB1 * NB1);
    int i  = (idx / NB1) % NB1;
    int k  = idx % NB1;
    const float4* q4 = (const float4*)qs[i];
    const float4* k4 = (const float4*)ks[ff * NB1 + k];
    float acc2 = 0.f;
    #pragma unroll
    for (int d4 = 0; d4 < 16; ++d4) {
      float4 qv = q4[d4], kv = k4[d4];
      acc2 += qv.x * kv.x + qv.y * kv.y + qv.z * kv.z + qv.w * kv.w;
    }
    Lbuf[(size_t)bid * (NF * NB1 * NB1) + idx] = acc2;
  }
}

// ---------------------------------------------------------------------------
// R[h,a,f,k,j,l] = sum_d rq_out[a,j,h,d] * rope(rk)[f,k,l,h,d]
// stored as Rbuf[(h*F+a)*B2 + j][fk*B2 + l]   (fk = f*B1+k)
// ---------------------------------------------------------------------------
__global__ __launch_bounds__(256)
void k_R(const float* __restrict__ rk, const float* __restrict__ cosb,
         const float* __restrict__ sinb, const float* __restrict__ rq_out,
         float* __restrict__ Rbuf) {
  const int bid = blockIdx.x;              // h*56 + fk
  const int h = bid / FB1;
  const int fk = bid % FB1;
  const int f = fk / NB1, k = fk % NB1;
  const int tid = threadIdx.x;
  __shared__ __align__(16) float ks[NB2][DD + 8];
  __shared__ __align__(16) float qs[FB2][DD + 8];
  for (int idx = tid; idx < NB2 * 32; idx += 256) {
    int l = idx >> 5, mm = idx & 31;
    int srow = f * (NB1 * NB2) + k * NB2 + l;
    const float* xr = rk + (size_t)srow * STRIDE_HD + h * DD;
    float x0 = xr[2 * mm], x1 = xr[2 * mm + 1];
    float co = cosb[srow * 32 + mm], si = sinb[srow * 32 + mm];
    ks[l][2 * mm]     = x0 * co - x1 * si;
    ks[l][2 * mm + 1] = x1 * co + x0 * si;
  }
  for (int idx = tid; idx < FB2 * DD; idx += 256) {
    int r2 = idx >> 6, d = idx & 63;
    qs[r2][d] = rq_out[(size_t)r2 * STRIDE_HD + h * DD + d];
  }
  __syncthreads();
  for (int idx = tid; idx < NF * NB2 * NB2; idx += 256) {   // 5408
    int aa = idx / (NB2 * NB2);
    int jj = (idx / NB2) % NB2;
    int l  = idx % NB2;
    const float4* q4 = (const float4*)qs[aa * NB2 + jj];
    const float4* k4 = (const float4*)ks[l];
    float acc2 = 0.f;
    #pragma unroll
    for (int d4 = 0; d4 < 16; ++d4) {
      float4 qv = q4[d4], kv = k4[d4];
      acc2 += qv.x * kv.x + qv.y * kv.y + qv.z * kv.z + qv.w * kv.w;
    }
    Rbuf[((size_t)(h * NF + aa) * NB2 + jj) * (size_t)(NF * NB1 * NB2)
         + (size_t)fk * NB2 + l] = acc2;
  }
}

// ---------------------------------------------------------------------------
// v (S,H,D) f32 -> vb[(h*64+d)*56 + fk][l 0..63] bf16, l>=52 zero padded
// ---------------------------------------------------------------------------
__global__ __launch_bounds__(256)
void k_vb(const float* __restrict__ v, unsigned short* __restrict__ vb) {
  const int fk = blockIdx.x;   // 0..55
  const int h = blockIdx.y;
  const int tid = threadIdx.x;
  __shared__ float tile[NB2][DD + 8];
  for (int idx = tid; idx < NB2 * DD; idx += 256) {
    int l = idx >> 6, d = idx & 63;
    tile[l][d] = v[(size_t)(fk * NB2 + l) * STRIDE_HD + h * DD + d];
  }
  __syncthreads();
  for (int idx = tid; idx < DD * 64; idx += 256) {
    int d = idx >> 6, l = idx & 63;
    float val = (l < NB2) ? tile[l][d] : 0.f;
    vb[((size_t)(h * DD + d) * FB1 + fk) * 64 + l] = f2bf(val);
  }
}

// ---------------------------------------------------------------------------
// Fused flash attention over the factorized score matrix.
// block = (h, a, j): 28 query rows i, keys t = (fk, l), 56 tiles of 52(+pad).
// ---------------------------------------------------------------------------
__global__ __launch_bounds__(256)
void k_main(const float* __restrict__ Lbuf, const float* __restrict__ Rbuf,
            const unsigned short* __restrict__ vb, float* __restrict__ outp) {
  const int bid = blockIdx.x;          // h*104 + a*52 + j
  const int h = bid / (NF * NB2);
  const int rem = bid % (NF * NB2);
  const int a = rem / NB2, j = rem % NB2;
  const int tid = threadIdx.x;
  const int lane = tid & 63;
  const int w = tid >> 6;

  __shared__ float Ls[NF * NB1 * NB1];     // [f][i][k]
  __shared__ float Rs[FB1][NB2];           // [fk][l]
  __shared__ float Rmx[FB1], Rmn[FB1];
  __shared__ __align__(16) unsigned short pt[32][72];
  __shared__ float m_l[32], r_l[32], l_l[32];

  for (int idx = tid; idx < NF * NB1 * NB1; idx += 256)
    Ls[idx] = Lbuf[(size_t)bid * (NF * NB1 * NB1) + idx];
  for (int idx = tid; idx < FB1 * NB2; idx += 256)
    ((float*)Rs)[idx] = Rbuf[(size_t)bid * (NF * NB1 * NB2) + idx];
  if (tid < 32) { m_l[tid] = -1e30f; l_l[tid] = 0.f; r_l[tid] = 0.f; }
  __syncthreads();
  if (tid < FB1) {
    float mx = -1e30f, mn = 1e30f;
    for (int l = 0; l < NB2; ++l) {
      float x2 = Rs[tid][l];
      mx = fmaxf(mx, x2); mn = fminf(mn, x2);
    }
    Rmx[tid] = mx; Rmn[tid] = mn;
  }
  __syncthreads();

  f32x4 acc0 = {0.f, 0.f, 0.f, 0.f}, acc1 = {0.f, 0.f, 0.f, 0.f};
  const int i_row = tid >> 3, sub = tid & 7;
  const int arow = (lane >> 4) * 4;
  const int koff = (lane >> 4) * 8;
  const size_t vbase = (size_t)(h * DD + w * 16 + (lane & 15)) * FB1 * 64;

  for (int fk = 0; fk < FB1; ++fk) {
    const int ff = fk / NB1, kk = fk % NB1;
    // phase 1: online-max update (exact tile max via Rmax/Rmin)
    if (sub == 0) {
      float m_old = m_l[i_row];
      float Lv = (i_row < NB1) ? Ls[ff * (NB1 * NB1) + i_row * NB1 + kk] : 0.f;
      float tmax = SCALEF * fmaxf(Lv * Rmx[fk], Lv * Rmn[fk]);
      float m_new = fmaxf(m_old, tmax);
      float r = __expf(m_old - m_new);
      m_l[i_row] = m_new;
      r_l[i_row] = r;
      l_l[i_row] *= r;
    }
    __syncthreads();
    // phase 2: p tile (bf16) + row partial sums
    {
      float m_new = m_l[i_row];
      float Lv = (i_row < NB1) ? Ls[ff * (NB1 * NB1) + i_row * NB1 + kk] : 0.f;
      float psum = 0.f;
      #pragma unroll
      for (int li = 0; li < 8; ++li) {
        int l = sub + li * 8;
        float pv = 0.f;
        if (l < NB2 && i_row < NB1) {
          float scv = SCALEF * (Lv * Rs[fk][l]);
          pv = __expf(scv - m_new);
          psum += pv;
        }
        pt[i_row][l] = f2bf(pv);
      }
      psum += __shfl_xor(psum, 1);
      psum += __shfl_xor(psum, 2);
      psum += __shfl_xor(psum, 4);
      if (sub == 0) l_l[i_row] += psum;
    }
    __syncthreads();
    // phase 3: rescale acc + MFMA (A = p tile, B = v tile)
    {
      float r00 = r_l[arow], r01 = r_l[arow + 1], r02 = r_l[arow + 2], r03 = r_l[arow + 3];
      float r10 = r_l[16 + arow], r11 = r_l[16 + arow + 1], r12 = r_l[16 + arow + 2], r13 = r_l[16 + arow + 3];
      acc0[0] *= r00; acc0[1] *= r01; acc0[2] *= r02; acc0[3] *= r03;
      acc1[0] *= r10; acc1[1] *= r11; acc1[2] *= r12; acc1[3] *= r13;
      const unsigned short* vptr = vb + vbase + (size_t)fk * 64 + koff;
      bf16x8 bf0 = *(const bf16x8*)(vptr);
      bf16x8 bf1 = *(const bf16x8*)(vptr + 32);
      bf16x8 a00 = *(const bf16x8*)&pt[(lane & 15)][koff];
      bf16x8 a01 = *(const bf16x8*)&pt[(lane & 15)][32 + koff];
      bf16x8 a10 = *(const bf16x8*)&pt[16 + (lane & 15)][koff];
      bf16x8 a11 = *(const bf16x8*)&pt[16 + (lane & 15)][32 + koff];
      acc0 = __builtin_amdgcn_mfma_f32_16x16x32_bf16(a00, bf0, acc0, 0, 0, 0);
      acc0 = __builtin_amdgcn_mfma_f32_16x16x32_bf16(a01, bf1, acc0, 0, 0, 0);
      acc1 = __builtin_amdgcn_mfma_f32_16x16x32_bf16(a10, bf0, acc1, 0, 0, 0);
      acc1 = __builtin_amdgcn_mfma_f32_16x16x32_bf16(a11, bf1, acc1, 0, 0, 0);
    }
    __syncthreads();
  }
  // epilogue: normalize + store
  {
    const int d = w * 16 + (lane & 15);
    #pragma unroll
    for (int q = 0; q < 4; ++q) {
      int i = arow + q;
      if (i < NB1) {
        int srow = a * (NB1 * NB2) + i * NB2 + j;
        outp[(size_t)srow * STRIDE_HD + h * DD + d] = acc0[q] / l_l[i];
      }
      int i2 = 16 + arow + q;
      if (i2 < NB1) {
        int srow2 = a * (NB1 * NB2) + i2 * NB2 + j;
        outp[(size_t)srow2 * STRIDE_HD + h * DD + d] = acc1[q] / l_l[i2];
      }
    }
  }
}

// ---------------------------------------------------------------------------
extern "C" void kernel_launch(void* const* d_in, const int* in_sizes, int n_in,
                              void* d_out, int out_size, void* d_ws, size_t ws_size,
                              hipStream_t stream) {
  (void)in_sizes; (void)n_in; (void)out_size; (void)ws_size;
  const float* lq   = (const float*)d_in[0];
  const float* lk   = (const float*)d_in[1];
  const float* rq   = (const float*)d_in[2];
  const float* rk   = (const float*)d_in[3];
  const float* v    = (const float*)d_in[4];
  const float* cosb = (const float*)d_in[5];
  const float* sinb = (const float*)d_in[6];
  const float* W_lkq = (const float*)d_in[7];  const float* b_lkq = (const float*)d_in[8];
  const float* W_lkk = (const float*)d_in[9];  const float* b_lkk = (const float*)d_in[10];
  const float* W_lkv = (const float*)d_in[11]; const float* b_lkv = (const float*)d_in[12];
  const float* W_rqq = (const float*)d_in[13]; const float* b_rqq = (const float*)d_in[14];
  const float* W_rqk = (const float*)d_in[15]; const float* b_rqk = (const float*)d_in[16];
  const float* W_rqv = (const float*)d_in[17]; const float* b_rqv = (const float*)d_in[18];

  float* ws = (float*)d_ws;
  float* lk_out = ws;                                               // 56*768
  float* rq_out = lk_out + (size_t)FB1 * STRIDE_HD;                 // 104*768
  float* Lbuf   = rq_out + (size_t)FB2 * STRIDE_HD;                 // 1248*1568
  float* Rbuf   = Lbuf + (size_t)HH * NF * NB2 * (NF * NB1 * NB1);  // 1248*2912
  unsigned short* vb =
      (unsigned short*)(Rbuf + (size_t)HH * NF * NB2 * (NF * NB1 * NB2)); // 12*64*56*64

  k_small<52, 28, 52, 1><<<dim3(56, 12), 256, 0, stream>>>(
      lk, cosb, sinb, W_lkq, b_lkq, W_lkk, b_lkk, W_lkv, b_lkv, lk_out);
  k_small<28, 52, 1, 52><<<dim3(104, 12), 256, 0, stream>>>(
      rq, cosb, sinb, W_rqq, b_rqq, W_rqk, b_rqk, W_rqv, b_rqv, rq_out);
  k_vb<<<dim3(56, 12), 256, 0, stream>>>(v, vb);
  k_L<<<1248, 256, 0, stream>>>(lq, cosb, sinb, lk_out, Lbuf);
  k_R<<<672, 256, 0, stream>>>(rk, cosb, sinb, rq_out, Rbuf);
  k_main<<<1248, 256, 0, stream>>>(Lbuf, Rbuf, vb, (float*)d_out);
}

// Round 2
// 224.006 us; speedup vs baseline: 1.2018x; 1.2018x over previous
//
#include <hip/hip_runtime.h>
#include <hip/hip_bf16.h>

#define HH 12
#define DD 64
#define NB1 28
#define NB2 52
#define NF 2
#define FB1 56           // NF*NB1
#define FB2 104          // NF*NB2
#define STRIDE_HD 768    // HH*DD
#define SCALEF 0.125f

typedef float f32x4 __attribute__((ext_vector_type(4)));
typedef short bf16x8 __attribute__((ext_vector_type(8)));

__device__ __forceinline__ unsigned short f2bf(float x) {
  union { float f; unsigned u; } c; c.f = x;
  unsigned r = c.u + 0x7fffu + ((c.u >> 16) & 1u);
  return (unsigned short)(r >> 16);
}

// ---------------------------------------------------------------------------
// Fused blin(+rope) + tiny SDPA + output rope for one (group, head).
// ---------------------------------------------------------------------------
template<int NK, int GD, int GMUL, int KSTR>
__global__ __launch_bounds__(256)
void k_small(const float* __restrict__ X,
             const float* __restrict__ cosb, const float* __restrict__ sinb,
             const float* __restrict__ Wq, const float* __restrict__ bq,
             const float* __restrict__ Wk, const float* __restrict__ bk,
             const float* __restrict__ Wv, const float* __restrict__ bv,
             float* __restrict__ outb) {
  const int n = blockIdx.x, h = blockIdx.y;
  const int tid = threadIdx.x;
  const int f = n / GD, g = n % GD;
  const int s_base = f * (NB1 * NB2) + g * GMUL;

  __shared__ __align__(16) float xs[NK][DD + 4];
  __shared__ float Ks[NK][DD + 1];
  __shared__ float Vs[NK][DD + 1];
  __shared__ float qs[DD];
  __shared__ float ps[64];

  for (int idx = tid; idx < NK * DD; idx += 256) {
    int r = idx >> 6, d = idx & 63;
    xs[r][d] = X[(size_t)(s_base + r * KSTR) * STRIDE_HD + h * DD + d];
  }
  __syncthreads();

  const int m  = tid >> 3;   // e-pair 0..31
  const int rg = tid & 7;    // row group 0..7
  const float* WkH = Wk + (size_t)h * DD * DD;
  const float* WvH = Wv + (size_t)h * DD * DD;
  const float bk0 = bk[h * DD + 2 * m], bk1 = bk[h * DD + 2 * m + 1];
  const float bv0 = bv[h * DD + 2 * m], bv1 = bv[h * DD + 2 * m + 1];
  const float4* wk0 = (const float4*)(WkH + (2 * m) * DD);
  const float4* wk1 = (const float4*)(WkH + (2 * m + 1) * DD);
  const float4* wv0 = (const float4*)(WvH + (2 * m) * DD);
  const float4* wv1 = (const float4*)(WvH + (2 * m + 1) * DD);

  for (int base = 0; base < NK; base += 16) {
    for (int rr = 0; rr < 2; ++rr) {
      int r = base + 2 * rg + rr;
      if (r < NK) {
        float k0 = bk0, k1 = bk1, v0 = bv0, v1 = bv1;
        const float4* x4 = (const float4*)xs[r];
        #pragma unroll
        for (int d4 = 0; d4 < 16; ++d4) {
          float4 xv = x4[d4];
          float4 a = wk0[d4], b = wk1[d4], c = wv0[d4], e = wv1[d4];
          k0 += xv.x * a.x + xv.y * a.y + xv.z * a.z + xv.w * a.w;
          k1 += xv.x * b.x + xv.y * b.y + xv.z * b.z + xv.w * b.w;
          v0 += xv.x * c.x + xv.y * c.y + xv.z * c.z + xv.w * c.w;
          v1 += xv.x * e.x + xv.y * e.y + xv.z * e.z + xv.w * e.w;
        }
        int srow = s_base + r * KSTR;
        float co = cosb[srow * 32 + m], si = sinb[srow * 32 + m];
        Ks[r][2 * m]     = k0 * co - k1 * si;
        Ks[r][2 * m + 1] = k1 * co + k0 * si;
        Vs[r][2 * m]     = v0;
        Vs[r][2 * m + 1] = v1;
      }
    }
  }
  if (rg == 0) {
    float q0 = bq[h * DD + 2 * m], q1 = bq[h * DD + 2 * m + 1];
    const float4* x4 = (const float4*)xs[0];
    const float4* w0 = (const float4*)(Wq + (size_t)h * DD * DD + (2 * m) * DD);
    const float4* w1 = (const float4*)(Wq + (size_t)h * DD * DD + (2 * m + 1) * DD);
    #pragma unroll
    for (int d4 = 0; d4 < 16; ++d4) {
      float4 xv = x4[d4];
      float4 a = w0[d4], b = w1[d4];
      q0 += xv.x * a.x + xv.y * a.y + xv.z * a.z + xv.w * a.w;
      q1 += xv.x * b.x + xv.y * b.y + xv.z * b.z + xv.w * b.w;
    }
    float co = cosb[s_base * 32 + m], si = sinb[s_base * 32 + m];
    qs[2 * m]     = q0 * co - q1 * si;
    qs[2 * m + 1] = q1 * co + q0 * si;
  }
  __syncthreads();

  if (tid < 64) {
    float sc = -1e30f;
    if (tid < NK) {
      float acc2 = 0.f;
      const float* kr = Ks[tid];
      #pragma unroll 8
      for (int d = 0; d < DD; ++d) acc2 += qs[d] * kr[d];
      sc = acc2 * SCALEF;
    }
    float mx = sc;
    for (int o = 32; o; o >>= 1) mx = fmaxf(mx, __shfl_xor(mx, o));
    float e = (tid < NK) ? __expf(sc - mx) : 0.f;
    float sm = e;
    for (int o = 32; o; o >>= 1) sm += __shfl_xor(sm, o);
    if (tid < NK) ps[tid] = e / sm;
  }
  __syncthreads();

  if (tid < 32) {
    float o0 = 0.f, o1 = 0.f;
    for (int r = 0; r < NK; ++r) {
      float p = ps[r];
      o0 += p * Vs[r][2 * tid];
      o1 += p * Vs[r][2 * tid + 1];
    }
    float co = cosb[s_base * 32 + tid], si = sinb[s_base * 32 + tid];
    outb[(size_t)n * STRIDE_HD + h * DD + 2 * tid]     = o0 * co - o1 * si;
    outb[(size_t)n * STRIDE_HD + h * DD + 2 * tid + 1] = o1 * co + o0 * si;
  }
}

// ---------------------------------------------------------------------------
// L: 2x2 register-blocked (halved LDS traffic vs per-dot loads)
// ---------------------------------------------------------------------------
__global__ __launch_bounds__(256)
void k_L(const float* __restrict__ lq, const float* __restrict__ cosb,
         const float* __restrict__ sinb, const float* __restrict__ lk_out,
         float* __restrict__ Lbuf) {
  const int bid = blockIdx.x;              // h*104 + a*52 + j
  const int h = bid / (NF * NB2);
  const int rem = bid % (NF * NB2);
  const int a = rem / NB2, j = rem % NB2;
  const int tid = threadIdx.x;
  __shared__ __align__(16) float qs[NB1][DD + 4];
  __shared__ __align__(16) float ks[FB1][DD + 4];
  for (int idx = tid; idx < NB1 * 32; idx += 256) {
    int i = idx >> 5, mm = idx & 31;
    int srow = a * (NB1 * NB2) + i * NB2 + j;
    const float* xr = lq + (size_t)srow * STRIDE_HD + h * DD;
    float x0 = xr[2 * mm], x1 = xr[2 * mm + 1];
    float co = cosb[srow * 32 + mm], si = sinb[srow * 32 + mm];
    qs[i][2 * mm]     = x0 * co - x1 * si;
    qs[i][2 * mm + 1] = x1 * co + x0 * si;
  }
  for (int idx = tid; idx < FB1 * DD; idx += 256) {
    int r = idx >> 6, d = idx & 63;
    ks[r][d] = lk_out[(size_t)r * STRIDE_HD + h * DD + d];
  }
  __syncthreads();
  for (int t = tid; t < NF * 14 * 14; t += 256) {   // 392 2x2 tiles
    int ff = t / 196, rr = t % 196;
    int it = rr / 14, kt = rr % 14;
    const float4* q0 = (const float4*)qs[2 * it];
    const float4* q1 = (const float4*)qs[2 * it + 1];
    const float4* k0 = (const float4*)ks[ff * NB1 + 2 * kt];
    const float4* k1 = (const float4*)ks[ff * NB1 + 2 * kt + 1];
    float a00 = 0.f, a01 = 0.f, a10 = 0.f, a11 = 0.f;
    #pragma unroll
    for (int d4 = 0; d4 < 16; ++d4) {
      float4 qa = q0[d4], qb = q1[d4], ka = k0[d4], kb = k1[d4];
      a00 += qa.x * ka.x + qa.y * ka.y + qa.z * ka.z + qa.w * ka.w;
      a01 += qa.x * kb.x + qa.y * kb.y + qa.z * kb.z + qa.w * kb.w;
      a10 += qb.x * ka.x + qb.y * ka.y + qb.z * ka.z + qb.w * ka.w;
      a11 += qb.x * kb.x + qb.y * kb.y + qb.z * kb.z + qb.w * kb.w;
    }
    size_t ob = (size_t)bid * (NF * NB1 * NB1) + (size_t)ff * (NB1 * NB1);
    Lbuf[ob + (size_t)(2 * it) * NB1 + 2 * kt]         = a00;
    Lbuf[ob + (size_t)(2 * it) * NB1 + 2 * kt + 1]     = a01;
    Lbuf[ob + (size_t)(2 * it + 1) * NB1 + 2 * kt]     = a10;
    Lbuf[ob + (size_t)(2 * it + 1) * NB1 + 2 * kt + 1] = a11;
  }
}

// ---------------------------------------------------------------------------
// R: 2x2 register-blocked
// ---------------------------------------------------------------------------
__global__ __launch_bounds__(256)
void k_R(const float* __restrict__ rk, const float* __restrict__ cosb,
         const float* __restrict__ sinb, const float* __restrict__ rq_out,
         float* __restrict__ Rbuf) {
  const int bid = blockIdx.x;              // h*56 + fk
  const int h = bid / FB1;
  const int fk = bid % FB1;
  const int f = fk / NB1, k = fk % NB1;
  const int tid = threadIdx.x;
  __shared__ __align__(16) float ks[NB2][DD + 4];
  __shared__ __align__(16) float qs[FB2][DD + 4];
  for (int idx = tid; idx < NB2 * 32; idx += 256) {
    int l = idx >> 5, mm = idx & 31;
    int srow = f * (NB1 * NB2) + k * NB2 + l;
    const float* xr = rk + (size_t)srow * STRIDE_HD + h * DD;
    float x0 = xr[2 * mm], x1 = xr[2 * mm + 1];
    float co = cosb[srow * 32 + mm], si = sinb[srow * 32 + mm];
    ks[l][2 * mm]     = x0 * co - x1 * si;
    ks[l][2 * mm + 1] = x1 * co + x0 * si;
  }
  for (int idx = tid; idx < FB2 * DD; idx += 256) {
    int r2 = idx >> 6, d = idx & 63;
    qs[r2][d] = rq_out[(size_t)r2 * STRIDE_HD + h * DD + d];
  }
  __syncthreads();
  for (int t = tid; t < NF * 26 * 26; t += 256) {   // 1352 2x2 tiles
    int aa = t / 676, rr = t % 676;
    int jt = rr / 26, lt = rr % 26;
    const float4* q0 = (const float4*)qs[aa * NB2 + 2 * jt];
    const float4* q1 = (const float4*)qs[aa * NB2 + 2 * jt + 1];
    const float4* k0 = (const float4*)ks[2 * lt];
    const float4* k1 = (const float4*)ks[2 * lt + 1];
    float a00 = 0.f, a01 = 0.f, a10 = 0.f, a11 = 0.f;
    #pragma unroll
    for (int d4 = 0; d4 < 16; ++d4) {
      float4 qa = q0[d4], qb = q1[d4], ka = k0[d4], kb = k1[d4];
      a00 += qa.x * ka.x + qa.y * ka.y + qa.z * ka.z + qa.w * ka.w;
      a01 += qa.x * kb.x + qa.y * kb.y + qa.z * kb.z + qa.w * kb.w;
      a10 += qb.x * ka.x + qb.y * ka.y + qb.z * ka.z + qb.w * ka.w;
      a11 += qb.x * kb.x + qb.y * kb.y + qb.z * kb.z + qb.w * kb.w;
    }
    size_t row0 = ((size_t)(h * NF + aa) * NB2 + 2 * jt) * (size_t)(NF * NB1 * NB2);
    size_t row1 = row0 + (size_t)(NF * NB1 * NB2);
    size_t cb = (size_t)fk * NB2 + 2 * lt;
    Rbuf[row0 + cb]     = a00;
    Rbuf[row0 + cb + 1] = a01;
    Rbuf[row1 + cb]     = a10;
    Rbuf[row1 + cb + 1] = a11;
  }
}

// ---------------------------------------------------------------------------
// v (S,H,D) f32 -> vb[(h*64+d)*56 + fk][l 0..63] bf16, l>=52 zero padded
// ---------------------------------------------------------------------------
__global__ __launch_bounds__(256)
void k_vb(const float* __restrict__ v, unsigned short* __restrict__ vb) {
  const int fk = blockIdx.x;
  const int h = blockIdx.y;
  const int tid = threadIdx.x;
  __shared__ float tile[NB2][DD + 8];
  for (int idx = tid; idx < NB2 * DD; idx += 256) {
    int l = idx >> 6, d = idx & 63;
    tile[l][d] = v[(size_t)(fk * NB2 + l) * STRIDE_HD + h * DD + d];
  }
  __syncthreads();
  for (int idx = tid; idx < DD * 64; idx += 256) {
    int d = idx >> 6, l = idx & 63;
    float val = (l < NB2) ? tile[l][d] : 0.f;
    vb[((size_t)(h * DD + d) * FB1 + fk) * 64 + l] = f2bf(val);
  }
}

// ---------------------------------------------------------------------------
// Fused flash attention over the factorized score matrix.
// Exact row max precomputed (no online rescaling); 1 barrier per K-tile.
// ---------------------------------------------------------------------------
__global__ __launch_bounds__(256)
void k_main(const float* __restrict__ Lbuf, const float* __restrict__ Rbuf,
            const unsigned short* __restrict__ vb, float* __restrict__ outp) {
  const int bid = blockIdx.x;          // h*104 + a*52 + j
  const int h = bid / (NF * NB2);
  const int rem = bid % (NF * NB2);
  const int a = rem / NB2, j = rem % NB2;
  const int tid = threadIdx.x;
  const int lane = tid & 63;
  const int w = tid >> 6;

  __shared__ __align__(16) float Ls2[NF * NB1 * NB1];   // pre-scaled by SCALEF
  __shared__ __align__(16) float Rs[FB1][56];           // 52 used + pad
  __shared__ float Rmx[FB1], Rmn[FB1];
  __shared__ __align__(16) unsigned short pt[2][32][72];
  __shared__ float m_l[NB1];
  __shared__ float linv[NB1];

  for (int idx = tid; idx < NF * NB1 * NB1; idx += 256)
    Ls2[idx] = Lbuf[(size_t)bid * (NF * NB1 * NB1) + idx] * SCALEF;
  for (int idx = tid; idx < FB1 * NB2; idx += 256) {
    int fk = idx / NB2, l = idx - fk * NB2;
    Rs[fk][l] = Rbuf[(size_t)bid * (NF * NB1 * NB2) + idx];
  }
  __syncthreads();

  // per-tile column max/min of R  +  prezero pt (pad rows/cols stay zero)
  if (tid < 224) {
    int fk = tid >> 2, part = tid & 3;
    float mx = -1e30f, mn = 1e30f;
    for (int l = part * 13; l < part * 13 + 13; ++l) {
      float x = Rs[fk][l];
      mx = fmaxf(mx, x); mn = fminf(mn, x);
    }
    mx = fmaxf(mx, __shfl_xor(mx, 1)); mn = fminf(mn, __shfl_xor(mn, 1));
    mx = fmaxf(mx, __shfl_xor(mx, 2)); mn = fminf(mn, __shfl_xor(mn, 2));
    if (part == 0) { Rmx[fk] = mx; Rmn[fk] = mn; }
  }
  {
    unsigned* pz = (unsigned*)pt;
    for (int idx = tid; idx < 2 * 32 * 72 / 2; idx += 256) pz[idx] = 0u;
  }
  __syncthreads();

  // exact per-row score max: m[i] = max_fk max(Lv*Rmx, Lv*Rmn)
  if (tid < 224) {
    int i = tid >> 3, s = tid & 7;
    float m = -1e30f;
    #pragma unroll
    for (int n = 0; n < 7; ++n) {
      int fk = s + 8 * n;
      int ff = fk / NB1, kk = fk - ff * NB1;
      float Lv = Ls2[ff * (NB1 * NB1) + i * NB1 + kk];
      m = fmaxf(m, fmaxf(Lv * Rmx[fk], Lv * Rmn[fk]));
    }
    m = fmaxf(m, __shfl_xor(m, 1));
    m = fmaxf(m, __shfl_xor(m, 2));
    m = fmaxf(m, __shfl_xor(m, 4));
    if (s == 0) m_l[i] = m;
  }
  __syncthreads();

  const int i_row = tid >> 3, sub = tid & 7;
  const bool act = (i_row < NB1) && (sub < 7);
  const float m2r = (i_row < NB1) ? m_l[i_row] : 0.f;
  const int koff = (lane >> 4) * 8;
  const int r0 = lane & 15, r1 = 16 + (lane & 15);
  const size_t vbase = (size_t)(h * DD + w * 16 + (lane & 15)) * (FB1 * 64);
  const unsigned short* vp = vb + vbase + koff;

  f32x4 acc0 = {0.f, 0.f, 0.f, 0.f}, acc1 = {0.f, 0.f, 0.f, 0.f};
  float lsum = 0.f;
  bf16x8 bf0 = *(const bf16x8*)(vp);
  bf16x8 bf1 = *(const bf16x8*)(vp + 32);
  int buf = 0;

  for (int fk = 0; fk < FB1; ++fk) {
    if (act) {
      const int ff = fk / NB1, kk = fk - ff * NB1;
      const float Lv = Ls2[ff * (NB1 * NB1) + i_row * NB1 + kk];
      const float4* rsp = (const float4*)&Rs[fk][sub * 8];
      float4 ra = rsp[0], rb = rsp[1];
      float p0 = __expf(fmaf(Lv, ra.x, -m2r));
      float p1 = __expf(fmaf(Lv, ra.y, -m2r));
      float p2 = __expf(fmaf(Lv, ra.z, -m2r));
      float p3 = __expf(fmaf(Lv, ra.w, -m2r));
      float p4 = __expf(fmaf(Lv, rb.x, -m2r));
      float p5 = __expf(fmaf(Lv, rb.y, -m2r));
      float p6 = __expf(fmaf(Lv, rb.z, -m2r));
      float p7 = __expf(fmaf(Lv, rb.w, -m2r));
      if (sub == 6) { p4 = 0.f; p5 = 0.f; p6 = 0.f; p7 = 0.f; }  // l=52..55 pad
      lsum += ((p0 + p1) + (p2 + p3)) + ((p4 + p5) + (p6 + p7));
      union { bf16x8 v8; __hip_bfloat162 h2[4]; } pk;
      pk.h2[0] = __float22bfloat162_rn(make_float2(p0, p1));
      pk.h2[1] = __float22bfloat162_rn(make_float2(p2, p3));
      pk.h2[2] = __float22bfloat162_rn(make_float2(p4, p5));
      pk.h2[3] = __float22bfloat162_rn(make_float2(p6, p7));
      *(bf16x8*)&pt[buf][i_row][sub * 8] = pk.v8;
    }
    __syncthreads();
    bf16x8 nb0 = bf0, nb1 = bf1;
    if (fk + 1 < FB1) {
      const unsigned short* np = vp + (fk + 1) * 64;
      nb0 = *(const bf16x8*)(np);
      nb1 = *(const bf16x8*)(np + 32);
    }
    bf16x8 a00 = *(const bf16x8*)&pt[buf][r0][koff];
    bf16x8 a01 = *(const bf16x8*)&pt[buf][r0][32 + koff];
    bf16x8 a10 = *(const bf16x8*)&pt[buf][r1][koff];
    bf16x8 a11 = *(const bf16x8*)&pt[buf][r1][32 + koff];
    acc0 = __builtin_amdgcn_mfma_f32_16x16x32_bf16(a00, bf0, acc0, 0, 0, 0);
    acc0 = __builtin_amdgcn_mfma_f32_16x16x32_bf16(a01, bf1, acc0, 0, 0, 0);
    acc1 = __builtin_amdgcn_mfma_f32_16x16x32_bf16(a10, bf0, acc1, 0, 0, 0);
    acc1 = __builtin_amdgcn_mfma_f32_16x16x32_bf16(a11, bf1, acc1, 0, 0, 0);
    bf0 = nb0; bf1 = nb1;
    buf ^= 1;
  }

  // row-sum reduce (within 8-thread groups, same wave) -> 1/l
  lsum += __shfl_xor(lsum, 1);
  lsum += __shfl_xor(lsum, 2);
  lsum += __shfl_xor(lsum, 4);
  if (sub == 0 && i_row < NB1) linv[i_row] = 1.0f / lsum;
  __syncthreads();

  {
    const int d = w * 16 + (lane & 15);
    const int arow = (lane >> 4) * 4;
    #pragma unroll
    for (int q = 0; q < 4; ++q) {
      int i = arow + q;
      if (i < NB1) {
        int srow = a * (NB1 * NB2) + i * NB2 + j;
        outp[(size_t)srow * STRIDE_HD + h * DD + d] = acc0[q] * linv[i];
      }
      int i2 = 16 + arow + q;
      if (i2 < NB1) {
        int srow2 = a * (NB1 * NB2) + i2 * NB2 + j;
        outp[(size_t)srow2 * STRIDE_HD + h * DD + d] = acc1[q] * linv[i2];
      }
    }
  }
}

// ---------------------------------------------------------------------------
extern "C" void kernel_launch(void* const* d_in, const int* in_sizes, int n_in,
                              void* d_out, int out_size, void* d_ws, size_t ws_size,
                              hipStream_t stream) {
  (void)in_sizes; (void)n_in; (void)out_size; (void)ws_size;
  const float* lq   = (const float*)d_in[0];
  const float* lk   = (const float*)d_in[1];
  const float* rq   = (const float*)d_in[2];
  const float* rk   = (const float*)d_in[3];
  const float* v    = (const float*)d_in[4];
  const float* cosb = (const float*)d_in[5];
  const float* sinb = (const float*)d_in[6];
  const float* W_lkq = (const float*)d_in[7];  const float* b_lkq = (const float*)d_in[8];
  const float* W_lkk = (const float*)d_in[9];  const float* b_lkk = (const float*)d_in[10];
  const float* W_lkv = (const float*)d_in[11]; const float* b_lkv = (const float*)d_in[12];
  const float* W_rqq = (const float*)d_in[13]; const float* b_rqq = (const float*)d_in[14];
  const float* W_rqk = (const float*)d_in[15]; const float* b_rqk = (const float*)d_in[16];
  const float* W_rqv = (const float*)d_in[17]; const float* b_rqv = (const float*)d_in[18];

  float* ws = (float*)d_ws;
  float* lk_out = ws;                                               // 56*768
  float* rq_out = lk_out + (size_t)FB1 * STRIDE_HD;                 // 104*768
  float* Lbuf   = rq_out + (size_t)FB2 * STRIDE_HD;                 // 1248*1568
  float* Rbuf   = Lbuf + (size_t)HH * NF * NB2 * (NF * NB1 * NB1);  // 1248*2912
  unsigned short* vb =
      (unsigned short*)(Rbuf + (size_t)HH * NF * NB2 * (NF * NB1 * NB2)); // 12*64*56*64

  k_small<52, 28, 52, 1><<<dim3(56, 12), 256, 0, stream>>>(
      lk, cosb, sinb, W_lkq, b_lkq, W_lkk, b_lkk, W_lkv, b_lkv, lk_out);
  k_small<28, 52, 1, 52><<<dim3(104, 12), 256, 0, stream>>>(
      rq, cosb, sinb, W_rqq, b_rqq, W_rqk, b_rqk, W_rqv, b_rqv, rq_out);
  k_vb<<<dim3(56, 12), 256, 0, stream>>>(v, vb);
  k_L<<<1248, 256, 0, stream>>>(lq, cosb, sinb, lk_out, Lbuf);
  k_R<<<672, 256, 0, stream>>>(rk, cosb, sinb, rq_out, Rbuf);
  k_main<<<1248, 256, 0, stream>>>(Lbuf, Rbuf, vb, (float*)d_out);
}